// Round 17
// baseline (388.281 us; speedup 1.0000x reference)
//
#include <hip/hip_runtime.h>
#include <hip/hip_cooperative_groups.h>

namespace cg = cooperative_groups;

#define D 128
#define HEADS 4

typedef __attribute__((ext_vector_type(8))) short short8;
typedef __attribute__((ext_vector_type(4))) short s16x4;
typedef __attribute__((ext_vector_type(4))) float f32x4;

// f32 -> bf16 (round to nearest even), bit pattern in short
__device__ __forceinline__ short f2b(float f) {
    unsigned u = __float_as_uint(f);
    unsigned r = (u + 0x7FFFu + ((u >> 16) & 1u)) >> 16;
    return (short)r;
}

__device__ __forceinline__ float fast_tanh(float x) {
    float e = __expf(2.0f * x);
    return 1.0f - 2.0f / (e + 1.0f);   // exact at +-inf; ~1e-7 rel err
}

// ---------- MFMA GEMM: C[M,128](bf16) = A[M,128] @ W[128,128] ----------
// 2 row-tiles (128 rows) per block; swapped-operand MFMA (row-major C frags);
// 8x8B C stores; register-space ns epilogue.
__global__ __launch_bounds__(256) void gemm_mfma(
    const unsigned short* __restrict__ Ab, const short* __restrict__ Wt,
    unsigned short* __restrict__ C, const float* __restrict__ att,
    float* __restrict__ ns, int buildmode, long Mrows,
    const int* __restrict__ ent_feature, const float* __restrict__ gw,
    const float* __restrict__ aw, const float* __restrict__ lw,
    const float* __restrict__ idemb, int num_ent)
{
    __shared__ short sA[64 * D];    // 16 KB, 16B granules XOR-swizzled by row&7
    __shared__ short sW[D * D];     // 32 KB
    __shared__ float attL[256];     // 1 KB att copy

    const int t = threadIdx.x;

    // ---- stage Wt once + att copy ----
    #pragma unroll
    for (int i = 0; i < 8; ++i) {
        int c = t + 256 * i;         // granule id
        int row = c >> 4, kb = c & 15;
        short8 blk = *(const short8*)(Wt + c * 8);
        *(short8*)&sW[row * D + (kb ^ (row & 7)) * 8] = blk;
    }
    attL[t] = att[t];

    for (int sub = 0; sub < 2; ++sub) {
        const long row0 = (long)blockIdx.x * 128 + sub * 64;
        if (row0 >= Mrows) break;          // uniform
        if (sub) __syncthreads();          // protect sA reuse

        // ---- stage A tile: 1 thread = 1 row-quarter (32 elems) ----
        {
            int srow = t >> 2;           // 0..63
            int q = t & 3;               // k-quarter
            long grow = row0 + srow;
            if (buildmode == 2) {
                const short8* p8 = (const short8*)(Ab + grow * D);
                #pragma unroll
                for (int jb = 0; jb < 4; ++jb) {
                    short8 blk = p8[q * 4 + jb];
                    int kb = (q * 4 + jb) ^ (srow & 7);
                    *(short8*)&sA[srow * D + kb * 8] = blk;
                }
            } else {
                const float* srcp;
                if (grow < num_ent)               srcp = idemb + grow * D;
                else if (grow < 2L * num_ent)     srcp = gw + (long)ent_feature[(grow - num_ent) * 3 + 0] * D;
                else if (grow < 3L * num_ent)     srcp = aw + (long)ent_feature[(grow - 2L * num_ent) * 3 + 1] * D;
                else                              srcp = lw + (long)ent_feature[(grow - 3L * num_ent) * 3 + 2] * D;
                const float4* p4 = (const float4*)srcp + q * 8;
                float v[32];
                #pragma unroll
                for (int j = 0; j < 8; ++j) {
                    float4 f = p4[j];
                    v[j * 4 + 0] = f.x; v[j * 4 + 1] = f.y; v[j * 4 + 2] = f.z; v[j * 4 + 3] = f.w;
                }
                #pragma unroll
                for (int jb = 0; jb < 4; ++jb) {
                    short8 blk;
                    #pragma unroll
                    for (int e = 0; e < 8; ++e) blk[e] = f2b(v[jb * 8 + e]);
                    int kb = (q * 4 + jb) ^ (srow & 7);
                    *(short8*)&sA[srow * D + kb * 8] = blk;
                }
            }
        }
        __syncthreads();

        // ---- MFMA (swapped operands): wave wv covers A-rows [wv*16, wv*16+16) ----
        const int wv = t >> 6, lane = t & 63;
        const int cl = lane & 15, kg = lane >> 4;

        short8 a[4];
        #pragma unroll
        for (int ks = 0; ks < 4; ++ks)
            a[ks] = *(const short8*)&sA[(wv * 16 + cl) * D + (((ks * 4 + kg) ^ (cl & 7)) * 8)];

        f32x4 acc[8];
        #pragma unroll
        for (int ct = 0; ct < 8; ++ct) acc[ct] = (f32x4){0.f, 0.f, 0.f, 0.f};

        #pragma unroll
        for (int ct = 0; ct < 8; ++ct) {
            #pragma unroll
            for (int ks = 0; ks < 4; ++ks) {
                short8 b = *(const short8*)&sW[(ct * 16 + cl) * D + (((ks * 4 + kg) ^ (cl & 7)) * 8)];
                acc[ct] = __builtin_amdgcn_mfma_f32_16x16x32_bf16(b, a[ks], acc[ct], 0, 0, 0);
            }
        }

        // ---- C store: lane holds C[row0+wv*16+cl][ct*16+kg*4 .. +3] per ct ----
        {
            unsigned short* Crow = C + (row0 + wv * 16 + cl) * D + kg * 4;
            #pragma unroll
            for (int ct = 0; ct < 8; ++ct) {
                s16x4 v;
                #pragma unroll
                for (int j = 0; j < 4; ++j) v[j] = f2b(acc[ct][j]);
                *(s16x4*)(Crow + ct * 16) = v;
            }
        }

        // ---- ns epilogue: per-lane partials + kg-axis reduction ----
        {
            float qp[4] = {0.f, 0.f, 0.f, 0.f};
            float sp[4] = {0.f, 0.f, 0.f, 0.f};
            #pragma unroll
            for (int ct = 0; ct < 8; ++ct) {
                int h = ct >> 1;
                int base = h * 64 + (ct & 1) * 16 + kg * 4;
                f32x4 aq4 = *(const f32x4*)&attL[base];
                f32x4 am4 = *(const f32x4*)&attL[base + 32];
                #pragma unroll
                for (int j = 0; j < 4; ++j) {
                    qp[h] = fmaf(acc[ct][j], aq4[j], qp[h]);
                    sp[h] = fmaf(acc[ct][j], am4[j], sp[h]);
                }
            }
            #pragma unroll
            for (int h = 0; h < 4; ++h) {
                qp[h] += __shfl_xor(qp[h], 16);
                qp[h] += __shfl_xor(qp[h], 32);
                sp[h] += __shfl_xor(sp[h], 16);
                sp[h] += __shfl_xor(sp[h], 32);
            }
            float qv = qp[0], sv = sp[0];
            if (kg == 1) { qv = qp[1]; sv = sp[1]; }
            else if (kg == 2) { qv = qp[2]; sv = sp[2]; }
            else if (kg == 3) { qv = qp[3]; sv = sp[3]; }
            long rown = row0 + wv * 16 + cl;
            ns[rown * 8 + kg] = qv;
            ns[rown * 8 + 4 + kg] = sv;
        }
    }
}

// ---------- prep1: fused {rw16_1 (bf16 r@W1), srt1, r1=r@Wr1, Wt1, Wt2} ----------
__global__ void prep1(const float* __restrict__ init_rel,
                      const float* __restrict__ W1, const float* __restrict__ Wr1,
                      const float* __restrict__ W2, const float* __restrict__ att1,
                      unsigned short* __restrict__ rw16, float* __restrict__ r1,
                      float* __restrict__ srt,
                      short* __restrict__ Wt1, short* __restrict__ Wt2, int nrel)
{
    __shared__ float red[128];
    int b = blockIdx.x, c = threadIdx.x;
    if (b >= 2 * nrel) {
        int bb = b - 2 * nrel;
        const float* W = (bb < D) ? W1 : W2;
        short* Wt = (bb < D) ? Wt1 : Wt2;
        int n = bb & (D - 1);
        Wt[n * D + c] = f2b(W[c * D + n]);
        return;
    }
    int r = (b < nrel) ? b : b - nrel;
    const float* W = (b < nrel) ? W1 : Wr1;
    float s = 0.f;
    for (int k = 0; k < D; ++k) s = fmaf(init_rel[r * D + k], W[k * D + c], s);
    if (b < nrel) {
        rw16[r * D + c] = (unsigned short)f2b(s);
        int h = c >> 5;
        red[c] = s * att1[h * 64 + 32 + (c & 31)];
        __syncthreads();
        if (c < 4) {
            float ss = 0.f;
            #pragma unroll
            for (int k = 0; k < 32; ++k) ss += red[c * 32 + k];
            srt[r * 4 + c] = ss;
        }
    } else {
        r1[r * D + c] = s;
    }
}

// ---------- prep2: fused {rw16_2 (bf16 r1@W2), srt2, r2=r1@Wr2} ----------
__global__ void prep2(const float* __restrict__ r1,
                      const float* __restrict__ W2, const float* __restrict__ Wr2,
                      const float* __restrict__ att2,
                      unsigned short* __restrict__ rw16, float* __restrict__ r2,
                      float* __restrict__ srt, int nrel)
{
    __shared__ float red[128];
    int b = blockIdx.x, c = threadIdx.x;
    int r = (b < nrel) ? b : b - nrel;
    const float* W = (b < nrel) ? W2 : Wr2;
    float s = 0.f;
    for (int k = 0; k < D; ++k) s = fmaf(r1[r * D + k], W[k * D + c], s);
    if (b < nrel) {
        rw16[r * D + c] = (unsigned short)f2b(s);
        int h = c >> 5;
        red[c] = s * att2[h * 64 + 32 + (c & 31)];
        __syncthreads();
        if (c < 4) {
            float ss = 0.f;
            #pragma unroll
            for (int k = 0; k < 32; ++k) ss += red[c * 32 + k];
            srt[r * 4 + c] = ss;
        }
    } else {
        r2[r * D + c] = s;
    }
}

// ---------- cooperative single-launch CSR build ----------
// grid = ceil(n/1024) blocks of 256 (all co-resident); phases split by grid.sync()
__global__ __launch_bounds__(256) void csr_build(
    const int* __restrict__ src, const int* __restrict__ dst,
    const int* __restrict__ etype,
    int* __restrict__ deg, int* __restrict__ offs, int* __restrict__ partial,
    unsigned* __restrict__ sorted, int n, int E_)
{
    cg::grid_group grid = cg::this_grid();
    __shared__ int lds[256];
    const int tid = blockIdx.x * 256 + threadIdx.x;
    const int nthreads = gridDim.x * 256;

    // phase 0: clear deg
    for (int i = tid; i < n; i += nthreads) deg[i] = 0;
    grid.sync();

    // phase 1: histogram
    for (int i = tid; i < E_; i += nthreads) atomicAdd(&deg[dst[i]], 1);
    grid.sync();

    // phase 2: per-block local exclusive scan of its 1024-chunk
    {
        int b = blockIdx.x, t = threadIdx.x;
        int base = b * 1024;
        int v[4]; int s = 0;
        #pragma unroll
        for (int j = 0; j < 4; ++j) {
            int idx = base + t * 4 + j;
            v[j] = idx < n ? deg[idx] : 0;
            s += v[j];
        }
        lds[t] = s;
        __syncthreads();
        int mysum = s;
        for (int off = 1; off < 256; off <<= 1) {
            int o = t >= off ? lds[t - off] : 0;
            __syncthreads();
            lds[t] += o;
            __syncthreads();
        }
        int excl = lds[t] - mysum;
        if (t == 255) partial[b] = lds[255];
        int run = excl;
        #pragma unroll
        for (int j = 0; j < 4; ++j) {
            int idx = base + t * 4 + j;
            if (idx < n) offs[idx] = run;
            run += v[j];
        }
    }
    grid.sync();

    // phase 3: block 0 scans the partials (gridDim <= 256)
    if (blockIdx.x == 0) {
        int t = threadIdx.x;
        int nb = gridDim.x;
        int v = (t < nb) ? partial[t] : 0;
        __syncthreads();           // lds reuse barrier
        lds[t] = v;
        __syncthreads();
        int my = v;
        for (int off = 1; off < 256; off <<= 1) {
            int o = (t >= off) ? lds[t - off] : 0;
            __syncthreads();
            lds[t] += o;
            __syncthreads();
        }
        if (t < nb) partial[t] = lds[t] - my;   // exclusive
        if (t == 255) offs[n] = lds[255];
    }
    grid.sync();

    // phase 4: apply block offsets
    for (int i = tid; i < n; i += nthreads) offs[i] += partial[i >> 10];
    grid.sync();

    // phase 5: scatter (deg as count-down cursor)
    for (int i = tid; i < E_; i += nthreads) {
        int d = dst[i];
        int pos = offs[d] + atomicSub(&deg[d], 1) - 1;
        sorted[pos] = ((unsigned)src[i] << 8) | (unsigned)etype[i];
    }
}

// ---------- fused per-node aggregation: inline score, grid-stride ----------
// 256-thread blocks = 4 waves; lane l covers elems [2l, 2l+1]; head = l>>4
#define GATHER_SLOT(mb, sv, rv, sr, p, cond)                                 \
    unsigned mb = 0, rv = 0; float sv = 0.f, sr = 0.f;                       \
    if (cond) { unsigned rowb = (p) & 0xFFFFFF00u;                           \
        unsigned etb = ((p) & 0xFFu) << 8;                                   \
        mb = *(const unsigned*)(xb + rowb + lo4);                            \
        sv = *(const float*)(nb + (rowb >> 3) + ho4);                        \
        rv = *(const unsigned*)(rb + etb + lo4);                             \
        sr = *(const float*)(sb + (etb >> 4) + (ho4 - 16)); }

#define ACCUM_SLOT(mb, sv, rv, sr, cond)                                     \
    if (cond) {                                                              \
        float mx = __uint_as_float(mb << 16) + __uint_as_float(rv << 16);    \
        float my = __uint_as_float(mb & 0xFFFF0000u) + __uint_as_float(rv & 0xFFFF0000u); \
        float sc = qd + sv + sr; sc = sc > 0.f ? sc : 0.2f * sc;             \
        float we = __expf(sc);                                               \
        srun += we; ax = fmaf(we, mx, ax); ay = fmaf(we, my, ay); }

__global__ __launch_bounds__(256) void agg_node(
    const int* __restrict__ offs, const unsigned* __restrict__ sedge,
    const unsigned short* __restrict__ xWb, const unsigned short* __restrict__ rw16,
    const float* __restrict__ ns, const float* __restrict__ srt,
    void* __restrict__ outx, int out_bf16, int Nn)
{
    int wid = threadIdx.x >> 6;
    int lane = threadIdx.x & 63;
    int h = lane >> 4;

    const char* xb = (const char*)xWb;
    const char* rb = (const char*)rw16;
    const char* nb = (const char*)ns;
    const char* sb = (const char*)srt;
    const int lo4 = 4 * lane;
    const int ho4 = 16 + 4 * h;      // sm part of ns row (+16 B); srt uses ho4-16

    const long wstride = (long)gridDim.x * 4;
    for (long node = (long)blockIdx.x * 4 + wid; node < Nn; node += wstride) {
        float qd = ns[node * 8 + h];
        int e0 = offs[node], e1 = offs[node + 1];
        float srun = 0.f, ax = 0.f, ay = 0.f;

        for (int base = e0; base < e1; base += 4) {
            unsigned p0 = sedge[base];
            unsigned p1 = (base + 1 < e1) ? sedge[base + 1] : 0;
            unsigned p2 = (base + 2 < e1) ? sedge[base + 2] : 0;
            unsigned p3 = (base + 3 < e1) ? sedge[base + 3] : 0;

            GATHER_SLOT(m0, v0, r0, s0, p0, true)
            GATHER_SLOT(m1, v1, r1, s1, p1, base + 1 < e1)
            GATHER_SLOT(m2, v2, r2, s2, p2, base + 2 < e1)
            GATHER_SLOT(m3, v3, r3, s3, p3, base + 3 < e1)

            ACCUM_SLOT(m0, v0, r0, s0, true)
            ACCUM_SLOT(m1, v1, r1, s1, base + 1 < e1)
            ACCUM_SLOT(m2, v2, r2, s2, base + 2 < e1)
            ACCUM_SLOT(m3, v3, r3, s3, base + 3 < e1)
        }

        float inv = 1.0f / (srun + 1e-16f);
        float ox = fast_tanh(ax * inv);
        float oy = fast_tanh(ay * inv);
        if (out_bf16) {
            unsigned pk = ((unsigned)(unsigned short)f2b(oy) << 16) | (unsigned short)f2b(ox);
            *(unsigned*)((unsigned short*)outx + node * D + 2 * lane) = pk;
        } else {
            float2 o; o.x = ox; o.y = oy;
            *(float2*)((float*)outx + node * D + 2 * lane) = o;
        }
    }
}

// ---------- combined output gathers: sub from out_x, rel from r2 ----------
__global__ void gather_out(const int* __restrict__ sub, const int* __restrict__ rel,
                           const float* __restrict__ xsrc, const float* __restrict__ rsrc,
                           float* __restrict__ out_sub, float* __restrict__ out_rel, int b)
{
    long i = (long)blockIdx.x * 256 + threadIdx.x;
    long tot = (long)b * 32;
    if (i < tot) {
        long row = i >> 5; int q = (int)(i & 31);
        ((float4*)out_sub)[i] = ((const float4*)(xsrc + (long)sub[row] * D))[q];
    } else if (i < 2 * tot) {
        long j = i - tot;
        long row = j >> 5; int q = (int)(j & 31);
        ((float4*)out_rel)[j] = ((const float4*)(rsrc + (long)rel[row] * D))[q];
    }
}

extern "C" void kernel_launch(void* const* d_in, const int* in_sizes, int n_in,
                              void* d_out, int out_size, void* d_ws, size_t ws_size,
                              hipStream_t stream)
{
    const int*   sub        = (const int*)d_in[0];
    const int*   rel        = (const int*)d_in[1];
    const int*   edge_index = (const int*)d_in[2];
    const int*   edge_type  = (const int*)d_in[3];
    const int*   ent_feat   = (const int*)d_in[4];
    const float* gw         = (const float*)d_in[5];
    const float* aw         = (const float*)d_in[6];
    const float* lw         = (const float*)d_in[7];
    const float* idemb      = (const float*)d_in[8];
    const float* init_rel   = (const float*)d_in[9];
    const float* W1         = (const float*)d_in[10];
    const float* Wr1        = (const float*)d_in[11];
    const float* att1       = (const float*)d_in[12];
    const float* W2         = (const float*)d_in[13];
    const float* Wr2        = (const float*)d_in[14];
    const float* att2       = (const float*)d_in[15];

    const int  Bn      = in_sizes[0];
    const int  E_      = in_sizes[3];
    const int  num_ent = in_sizes[4] / 3;
    const long Nn      = 4L * num_ent;
    const int  nrel    = in_sizes[9] / D;

    const int* srcp = edge_index;
    const int* dstp = edge_index + E_;

    float* out_sub = (float*)d_out;
    float* out_rel = out_sub + (long)Bn * D;
    float* out_x   = out_rel + (long)Bn * D;   // N x 128 final x (f32)

    unsigned short* xWb = (unsigned short*)d_ws;       // N x 128 bf16
    unsigned short* x1b = xWb + Nn * D;                // N x 128 bf16
    int*      offs   = (int*)(x1b + Nn * D);           // N+4 (padded)
    int*      deg    = offs + (Nn + 4);                // N (also scatter cursor)
    unsigned* sorted = (unsigned*)(deg + Nn);          // E packed (src<<8)|et
    int*      partial= (int*)(sorted + E_);            // block partials (1024)
    unsigned short* rw16 = (unsigned short*)(partial + 1024);  // nrel x 128 bf16
    float* r1     = (float*)(rw16 + (long)nrel * D);
    float* r2     = r1 + (long)nrel * D;
    short* Wt1    = (short*)(r2 + (long)nrel * D);     // 128x128 bf16
    short* Wt2    = Wt1 + D * D;
    float* ns     = (float*)(Wt2 + D * D);             // N x 8
    float* srt    = ns + Nn * 8;                       // nrel x 4

    dim3 blk(256);
    int gemm_blocks  = (int)((Nn + 127) / 128);
    int agg_blocks   = 2048;                           // grid-stride
    int gat_blocks   = (int)((2L * Bn * 32 + 255) / 256);
    int csr_blocks   = (int)((Nn + 1023) / 1024);      // <= 256 required

    // ---------------- prep1: Wt transposes + rel GEMMs + srt1 ----------------
    prep1<<<2 * nrel + 256, D, 0, stream>>>(init_rel, W1, Wr1, W2, att1,
                                            rw16, r1, srt, Wt1, Wt2, nrel);

    // ---------------- CSR build: single cooperative launch ----------------
    {
        int n_i = (int)Nn, e_i = E_;
        void* args[] = { (void*)&srcp, (void*)&dstp, (void*)&edge_type,
                         (void*)&deg, (void*)&offs, (void*)&partial,
                         (void*)&sorted, (void*)&n_i, (void*)&e_i };
        hipLaunchCooperativeKernel((void*)csr_build, dim3(csr_blocks), blk,
                                   args, 0, stream);
    }

    // ---------------- Layer 1 ----------------
    gemm_mfma<<<gemm_blocks, blk, 0, stream>>>(nullptr, Wt1, xWb, att1, ns, 1, Nn,
                                               ent_feat, gw, aw, lw, idemb, num_ent);
    agg_node<<<agg_blocks, blk, 0, stream>>>(offs, sorted, xWb, rw16, ns, srt, x1b, 1, (int)Nn);

    // ---------------- Layer 2 ----------------
    prep2<<<2 * nrel, D, 0, stream>>>(r1, W2, Wr2, att2, rw16, r2, srt, nrel);
    gemm_mfma<<<gemm_blocks, blk, 0, stream>>>(x1b, Wt2, xWb, att2, ns, 2, Nn,
                                               nullptr, nullptr, nullptr, nullptr, nullptr, num_ent);
    agg_node<<<agg_blocks, blk, 0, stream>>>(offs, sorted, xWb, rw16, ns, srt, out_x, 0, (int)Nn);

    // ---------------- outputs ----------------
    gather_out<<<gat_blocks, blk, 0, stream>>>(sub, rel, out_x, r2, out_sub, out_rel, Bn);
}

// Round 18
// 276.686 us; speedup vs baseline: 1.4033x; 1.4033x over previous
//
#include <hip/hip_runtime.h>

#define D 128
#define HEADS 4

typedef __attribute__((ext_vector_type(8))) short short8;
typedef __attribute__((ext_vector_type(4))) short s16x4;
typedef __attribute__((ext_vector_type(4))) float f32x4;

// f32 -> bf16 (round to nearest even), bit pattern in short
__device__ __forceinline__ short f2b(float f) {
    unsigned u = __float_as_uint(f);
    unsigned r = (u + 0x7FFFu + ((u >> 16) & 1u)) >> 16;
    return (short)r;
}

__device__ __forceinline__ float fast_tanh(float x) {
    float e = __expf(2.0f * x);
    return 1.0f - 2.0f / (e + 1.0f);   // exact at +-inf; ~1e-7 rel err
}

// ---------- MFMA GEMM: C[M,128](bf16) = A[M,128] @ W[128,128] ----------
// 2 row-tiles (128 rows) per block; swapped-operand MFMA (row-major C frags);
// 8x8B C stores; register-space ns epilogue.
__global__ __launch_bounds__(256) void gemm_mfma(
    const unsigned short* __restrict__ Ab, const short* __restrict__ Wt,
    unsigned short* __restrict__ C, const float* __restrict__ att,
    float* __restrict__ ns, int buildmode, long Mrows,
    const int* __restrict__ ent_feature, const float* __restrict__ gw,
    const float* __restrict__ aw, const float* __restrict__ lw,
    const float* __restrict__ idemb, int num_ent)
{
    __shared__ short sA[64 * D];    // 16 KB, 16B granules XOR-swizzled by row&7
    __shared__ short sW[D * D];     // 32 KB
    __shared__ float attL[256];     // 1 KB att copy

    const int t = threadIdx.x;

    // ---- stage Wt once + att copy ----
    #pragma unroll
    for (int i = 0; i < 8; ++i) {
        int c = t + 256 * i;         // granule id
        int row = c >> 4, kb = c & 15;
        short8 blk = *(const short8*)(Wt + c * 8);
        *(short8*)&sW[row * D + (kb ^ (row & 7)) * 8] = blk;
    }
    attL[t] = att[t];

    for (int sub = 0; sub < 2; ++sub) {
        const long row0 = (long)blockIdx.x * 128 + sub * 64;
        if (row0 >= Mrows) break;          // uniform
        if (sub) __syncthreads();          // protect sA reuse

        // ---- stage A tile: 1 thread = 1 row-quarter (32 elems) ----
        {
            int srow = t >> 2;           // 0..63
            int q = t & 3;               // k-quarter
            long grow = row0 + srow;
            if (buildmode == 2) {
                const short8* p8 = (const short8*)(Ab + grow * D);
                #pragma unroll
                for (int jb = 0; jb < 4; ++jb) {
                    short8 blk = p8[q * 4 + jb];
                    int kb = (q * 4 + jb) ^ (srow & 7);
                    *(short8*)&sA[srow * D + kb * 8] = blk;
                }
            } else {
                const float* srcp;
                if (grow < num_ent)               srcp = idemb + grow * D;
                else if (grow < 2L * num_ent)     srcp = gw + (long)ent_feature[(grow - num_ent) * 3 + 0] * D;
                else if (grow < 3L * num_ent)     srcp = aw + (long)ent_feature[(grow - 2L * num_ent) * 3 + 1] * D;
                else                              srcp = lw + (long)ent_feature[(grow - 3L * num_ent) * 3 + 2] * D;
                const float4* p4 = (const float4*)srcp + q * 8;
                float v[32];
                #pragma unroll
                for (int j = 0; j < 8; ++j) {
                    float4 f = p4[j];
                    v[j * 4 + 0] = f.x; v[j * 4 + 1] = f.y; v[j * 4 + 2] = f.z; v[j * 4 + 3] = f.w;
                }
                #pragma unroll
                for (int jb = 0; jb < 4; ++jb) {
                    short8 blk;
                    #pragma unroll
                    for (int e = 0; e < 8; ++e) blk[e] = f2b(v[jb * 8 + e]);
                    int kb = (q * 4 + jb) ^ (srow & 7);
                    *(short8*)&sA[srow * D + kb * 8] = blk;
                }
            }
        }
        __syncthreads();

        // ---- MFMA (swapped operands): wave wv covers A-rows [wv*16, wv*16+16) ----
        const int wv = t >> 6, lane = t & 63;
        const int cl = lane & 15, kg = lane >> 4;

        short8 a[4];
        #pragma unroll
        for (int ks = 0; ks < 4; ++ks)
            a[ks] = *(const short8*)&sA[(wv * 16 + cl) * D + (((ks * 4 + kg) ^ (cl & 7)) * 8)];

        f32x4 acc[8];
        #pragma unroll
        for (int ct = 0; ct < 8; ++ct) acc[ct] = (f32x4){0.f, 0.f, 0.f, 0.f};

        #pragma unroll
        for (int ct = 0; ct < 8; ++ct) {
            #pragma unroll
            for (int ks = 0; ks < 4; ++ks) {
                short8 b = *(const short8*)&sW[(ct * 16 + cl) * D + (((ks * 4 + kg) ^ (cl & 7)) * 8)];
                acc[ct] = __builtin_amdgcn_mfma_f32_16x16x32_bf16(b, a[ks], acc[ct], 0, 0, 0);
            }
        }

        // ---- C store: lane holds C[row0+wv*16+cl][ct*16+kg*4 .. +3] per ct ----
        {
            unsigned short* Crow = C + (row0 + wv * 16 + cl) * D + kg * 4;
            #pragma unroll
            for (int ct = 0; ct < 8; ++ct) {
                s16x4 v;
                #pragma unroll
                for (int j = 0; j < 4; ++j) v[j] = f2b(acc[ct][j]);
                *(s16x4*)(Crow + ct * 16) = v;
            }
        }

        // ---- ns epilogue: per-lane partials + kg-axis reduction ----
        {
            float qp[4] = {0.f, 0.f, 0.f, 0.f};
            float sp[4] = {0.f, 0.f, 0.f, 0.f};
            #pragma unroll
            for (int ct = 0; ct < 8; ++ct) {
                int h = ct >> 1;
                int base = h * 64 + (ct & 1) * 16 + kg * 4;
                f32x4 aq4 = *(const f32x4*)&attL[base];
                f32x4 am4 = *(const f32x4*)&attL[base + 32];
                #pragma unroll
                for (int j = 0; j < 4; ++j) {
                    qp[h] = fmaf(acc[ct][j], aq4[j], qp[h]);
                    sp[h] = fmaf(acc[ct][j], am4[j], sp[h]);
                }
            }
            #pragma unroll
            for (int h = 0; h < 4; ++h) {
                qp[h] += __shfl_xor(qp[h], 16);
                qp[h] += __shfl_xor(qp[h], 32);
                sp[h] += __shfl_xor(sp[h], 16);
                sp[h] += __shfl_xor(sp[h], 32);
            }
            float qv = qp[0], sv = sp[0];
            if (kg == 1) { qv = qp[1]; sv = sp[1]; }
            else if (kg == 2) { qv = qp[2]; sv = sp[2]; }
            else if (kg == 3) { qv = qp[3]; sv = sp[3]; }
            long rown = row0 + wv * 16 + cl;
            ns[rown * 8 + kg] = qv;
            ns[rown * 8 + 4 + kg] = sv;
        }
    }
}

// ---------- prep1: fused {rw16_1 (bf16 r@W1), srt1, r1=r@Wr1, Wt1, Wt2} ----------
__global__ void prep1(const float* __restrict__ init_rel,
                      const float* __restrict__ W1, const float* __restrict__ Wr1,
                      const float* __restrict__ W2, const float* __restrict__ att1,
                      unsigned short* __restrict__ rw16, float* __restrict__ r1,
                      float* __restrict__ srt,
                      short* __restrict__ Wt1, short* __restrict__ Wt2, int nrel)
{
    __shared__ float red[128];
    int b = blockIdx.x, c = threadIdx.x;
    if (b >= 2 * nrel) {
        int bb = b - 2 * nrel;
        const float* W = (bb < D) ? W1 : W2;
        short* Wt = (bb < D) ? Wt1 : Wt2;
        int n = bb & (D - 1);
        Wt[n * D + c] = f2b(W[c * D + n]);
        return;
    }
    int r = (b < nrel) ? b : b - nrel;
    const float* W = (b < nrel) ? W1 : Wr1;
    float s = 0.f;
    for (int k = 0; k < D; ++k) s = fmaf(init_rel[r * D + k], W[k * D + c], s);
    if (b < nrel) {
        rw16[r * D + c] = (unsigned short)f2b(s);
        int h = c >> 5;
        red[c] = s * att1[h * 64 + 32 + (c & 31)];
        __syncthreads();
        if (c < 4) {
            float ss = 0.f;
            #pragma unroll
            for (int k = 0; k < 32; ++k) ss += red[c * 32 + k];
            srt[r * 4 + c] = ss;
        }
    } else {
        r1[r * D + c] = s;
    }
}

// ---------- prep2: fused {rw16_2 (bf16 r1@W2), srt2, r2=r1@Wr2} ----------
__global__ void prep2(const float* __restrict__ r1,
                      const float* __restrict__ W2, const float* __restrict__ Wr2,
                      const float* __restrict__ att2,
                      unsigned short* __restrict__ rw16, float* __restrict__ r2,
                      float* __restrict__ srt, int nrel)
{
    __shared__ float red[128];
    int b = blockIdx.x, c = threadIdx.x;
    int r = (b < nrel) ? b : b - nrel;
    const float* W = (b < nrel) ? W2 : Wr2;
    float s = 0.f;
    for (int k = 0; k < D; ++k) s = fmaf(r1[r * D + k], W[k * D + c], s);
    if (b < nrel) {
        rw16[r * D + c] = (unsigned short)f2b(s);
        int h = c >> 5;
        red[c] = s * att2[h * 64 + 32 + (c & 31)];
        __syncthreads();
        if (c < 4) {
            float ss = 0.f;
            #pragma unroll
            for (int k = 0; k < 32; ++k) ss += red[c * 32 + k];
            srt[r * 4 + c] = ss;
        }
    } else {
        r2[r * D + c] = s;
    }
}

// ---------- CSR build (split kernels) ----------
__global__ __launch_bounds__(256) void hist_deg(const int* __restrict__ dst,
                                                int* __restrict__ deg, int E_)
{
    int i = blockIdx.x * 256 + threadIdx.x;
    if (i < E_) atomicAdd(&deg[dst[i]], 1);
}

__global__ __launch_bounds__(256) void scan_local(const int* __restrict__ deg,
                                                  int* __restrict__ offs,
                                                  int* __restrict__ partial, int n)
{
    __shared__ int lds[256];
    int b = blockIdx.x, t = threadIdx.x;
    int base = b * 1024;
    int v[4]; int s = 0;
    #pragma unroll
    for (int j = 0; j < 4; ++j) {
        int idx = base + t * 4 + j;
        v[j] = idx < n ? deg[idx] : 0;
        s += v[j];
    }
    lds[t] = s;
    __syncthreads();
    int mysum = s;
    for (int off = 1; off < 256; off <<= 1) {
        int o = t >= off ? lds[t - off] : 0;
        __syncthreads();
        lds[t] += o;
        __syncthreads();
    }
    int excl = lds[t] - mysum;
    if (t == 255) partial[b] = lds[255];
    int run = excl;
    #pragma unroll
    for (int j = 0; j < 4; ++j) {
        int idx = base + t * 4 + j;
        if (idx < n) offs[idx] = run;
        run += v[j];
    }
}

// parallel scan of block partials (nb <= 256), one 256-thread block
__global__ void scan_partials(int* __restrict__ partial, int nb,
                              int* __restrict__ offs, int n)
{
    __shared__ int lds[256];
    int t = threadIdx.x;
    int v = (t < nb) ? partial[t] : 0;
    lds[t] = v;
    __syncthreads();
    int my = v;
    for (int off = 1; off < 256; off <<= 1) {
        int o = (t >= off) ? lds[t - off] : 0;
        __syncthreads();
        lds[t] += o;
        __syncthreads();
    }
    if (t < nb) partial[t] = lds[t] - my;    // exclusive
    if (t == 255) offs[n] = lds[255];
}

__global__ __launch_bounds__(256) void scan_add(int* __restrict__ offs,
                                                const int* __restrict__ partial, int n)
{
    int idx = blockIdx.x * 256 + threadIdx.x;
    if (idx < n) offs[idx] += partial[idx >> 10];
}

// scatter: cursor = deg counting down (atomicSub); pack (src<<8)|etype
__global__ __launch_bounds__(256) void scatter_edges(
    const int* __restrict__ src, const int* __restrict__ dst, const int* __restrict__ etype,
    const int* __restrict__ offs, int* __restrict__ deg,
    unsigned* __restrict__ sorted, int E_)
{
    int i = blockIdx.x * 256 + threadIdx.x;
    if (i >= E_) return;
    int d = dst[i];
    int pos = offs[d] + atomicSub(&deg[d], 1) - 1;
    sorted[pos] = ((unsigned)src[i] << 8) | (unsigned)etype[i];
}

// ---------- fused per-node aggregation: inline score, grid-stride ----------
// 256-thread blocks = 4 waves; lane l covers elems [2l, 2l+1]; head = l>>4
#define GATHER_SLOT(mb, sv, rv, sr, p, cond)                                 \
    unsigned mb = 0, rv = 0; float sv = 0.f, sr = 0.f;                       \
    if (cond) { unsigned rowb = (p) & 0xFFFFFF00u;                           \
        unsigned etb = ((p) & 0xFFu) << 8;                                   \
        mb = *(const unsigned*)(xb + rowb + lo4);                            \
        sv = *(const float*)(nb + (rowb >> 3) + ho4);                        \
        rv = *(const unsigned*)(rb + etb + lo4);                             \
        sr = *(const float*)(sb + (etb >> 4) + (ho4 - 16)); }

#define ACCUM_SLOT(mb, sv, rv, sr, cond)                                     \
    if (cond) {                                                              \
        float mx = __uint_as_float(mb << 16) + __uint_as_float(rv << 16);    \
        float my = __uint_as_float(mb & 0xFFFF0000u) + __uint_as_float(rv & 0xFFFF0000u); \
        float sc = qd + sv + sr; sc = sc > 0.f ? sc : 0.2f * sc;             \
        float we = __expf(sc);                                               \
        srun += we; ax = fmaf(we, mx, ax); ay = fmaf(we, my, ay); }

__global__ __launch_bounds__(256) void agg_node(
    const int* __restrict__ offs, const unsigned* __restrict__ sedge,
    const unsigned short* __restrict__ xWb, const unsigned short* __restrict__ rw16,
    const float* __restrict__ ns, const float* __restrict__ srt,
    void* __restrict__ outx, int out_bf16, int Nn)
{
    int wid = threadIdx.x >> 6;
    int lane = threadIdx.x & 63;
    int h = lane >> 4;

    const char* xb = (const char*)xWb;
    const char* rb = (const char*)rw16;
    const char* nb = (const char*)ns;
    const char* sb = (const char*)srt;
    const int lo4 = 4 * lane;
    const int ho4 = 16 + 4 * h;      // sm part of ns row (+16 B); srt uses ho4-16

    const long wstride = (long)gridDim.x * 4;
    for (long node = (long)blockIdx.x * 4 + wid; node < Nn; node += wstride) {
        float qd = ns[node * 8 + h];
        int e0 = offs[node], e1 = offs[node + 1];
        float srun = 0.f, ax = 0.f, ay = 0.f;

        for (int base = e0; base < e1; base += 4) {
            unsigned p0 = sedge[base];
            unsigned p1 = (base + 1 < e1) ? sedge[base + 1] : 0;
            unsigned p2 = (base + 2 < e1) ? sedge[base + 2] : 0;
            unsigned p3 = (base + 3 < e1) ? sedge[base + 3] : 0;

            GATHER_SLOT(m0, v0, r0, s0, p0, true)
            GATHER_SLOT(m1, v1, r1, s1, p1, base + 1 < e1)
            GATHER_SLOT(m2, v2, r2, s2, p2, base + 2 < e1)
            GATHER_SLOT(m3, v3, r3, s3, p3, base + 3 < e1)

            ACCUM_SLOT(m0, v0, r0, s0, true)
            ACCUM_SLOT(m1, v1, r1, s1, base + 1 < e1)
            ACCUM_SLOT(m2, v2, r2, s2, base + 2 < e1)
            ACCUM_SLOT(m3, v3, r3, s3, base + 3 < e1)
        }

        float inv = 1.0f / (srun + 1e-16f);
        float ox = fast_tanh(ax * inv);
        float oy = fast_tanh(ay * inv);
        if (out_bf16) {
            unsigned pk = ((unsigned)(unsigned short)f2b(oy) << 16) | (unsigned short)f2b(ox);
            *(unsigned*)((unsigned short*)outx + node * D + 2 * lane) = pk;
        } else {
            float2 o; o.x = ox; o.y = oy;
            *(float2*)((float*)outx + node * D + 2 * lane) = o;
        }
    }
}

// ---------- combined output gathers: sub from out_x, rel from r2 ----------
__global__ void gather_out(const int* __restrict__ sub, const int* __restrict__ rel,
                           const float* __restrict__ xsrc, const float* __restrict__ rsrc,
                           float* __restrict__ out_sub, float* __restrict__ out_rel, int b)
{
    long i = (long)blockIdx.x * 256 + threadIdx.x;
    long tot = (long)b * 32;
    if (i < tot) {
        long row = i >> 5; int q = (int)(i & 31);
        ((float4*)out_sub)[i] = ((const float4*)(xsrc + (long)sub[row] * D))[q];
    } else if (i < 2 * tot) {
        long j = i - tot;
        long row = j >> 5; int q = (int)(j & 31);
        ((float4*)out_rel)[j] = ((const float4*)(rsrc + (long)rel[row] * D))[q];
    }
}

extern "C" void kernel_launch(void* const* d_in, const int* in_sizes, int n_in,
                              void* d_out, int out_size, void* d_ws, size_t ws_size,
                              hipStream_t stream)
{
    const int*   sub        = (const int*)d_in[0];
    const int*   rel        = (const int*)d_in[1];
    const int*   edge_index = (const int*)d_in[2];
    const int*   edge_type  = (const int*)d_in[3];
    const int*   ent_feat   = (const int*)d_in[4];
    const float* gw         = (const float*)d_in[5];
    const float* aw         = (const float*)d_in[6];
    const float* lw         = (const float*)d_in[7];
    const float* idemb      = (const float*)d_in[8];
    const float* init_rel   = (const float*)d_in[9];
    const float* W1         = (const float*)d_in[10];
    const float* Wr1        = (const float*)d_in[11];
    const float* att1       = (const float*)d_in[12];
    const float* W2         = (const float*)d_in[13];
    const float* Wr2        = (const float*)d_in[14];
    const float* att2       = (const float*)d_in[15];

    const int  Bn      = in_sizes[0];
    const int  E_      = in_sizes[3];
    const int  num_ent = in_sizes[4] / 3;
    const long Nn      = 4L * num_ent;
    const int  nrel    = in_sizes[9] / D;

    const int* srcp = edge_index;
    const int* dstp = edge_index + E_;

    float* out_sub = (float*)d_out;
    float* out_rel = out_sub + (long)Bn * D;
    float* out_x   = out_rel + (long)Bn * D;   // N x 128 final x (f32)

    unsigned short* xWb = (unsigned short*)d_ws;       // N x 128 bf16
    unsigned short* x1b = xWb + Nn * D;                // N x 128 bf16
    int*      offs   = (int*)(x1b + Nn * D);           // N+4 (padded)
    int*      deg    = offs + (Nn + 4);                // N (also scatter cursor)
    unsigned* sorted = (unsigned*)(deg + Nn);          // E packed (src<<8)|et
    int*      partial= (int*)(sorted + E_);            // block partials (1024)
    unsigned short* rw16 = (unsigned short*)(partial + 1024);  // nrel x 128 bf16
    float* r1     = (float*)(rw16 + (long)nrel * D);
    float* r2     = r1 + (long)nrel * D;
    short* Wt1    = (short*)(r2 + (long)nrel * D);     // 128x128 bf16
    short* Wt2    = Wt1 + D * D;
    float* ns     = (float*)(Wt2 + D * D);             // N x 8
    float* srt    = ns + Nn * 8;                       // nrel x 4

    dim3 blk(256);
    int gemm_blocks  = (int)((Nn + 127) / 128);
    int e_blocks     = (E_ + 255) / 256;
    int agg_blocks   = 2048;                           // grid-stride
    int gat_blocks   = (int)((2L * Bn * 32 + 255) / 256);
    int scan_blocks  = (int)((Nn + 1023) / 1024);
    int sadd_blocks  = (int)((Nn + 255) / 256);

    // ---------------- prep1: Wt transposes + rel GEMMs + srt1 ----------------
    prep1<<<2 * nrel + 256, D, 0, stream>>>(init_rel, W1, Wr1, W2, att1,
                                            rw16, r1, srt, Wt1, Wt2, nrel);

    // ---------------- CSR build (by dst), split kernels ----------------
    hipMemsetAsync(deg, 0, Nn * sizeof(int), stream);
    hist_deg<<<e_blocks, blk, 0, stream>>>(dstp, deg, E_);
    scan_local<<<scan_blocks, blk, 0, stream>>>(deg, offs, partial, (int)Nn);
    scan_partials<<<1, 256, 0, stream>>>(partial, scan_blocks, offs, (int)Nn);
    scan_add<<<sadd_blocks, blk, 0, stream>>>(offs, partial, (int)Nn);
    scatter_edges<<<e_blocks, blk, 0, stream>>>(srcp, dstp, edge_type, offs, deg, sorted, E_);

    // ---------------- Layer 1 ----------------
    gemm_mfma<<<gemm_blocks, blk, 0, stream>>>(nullptr, Wt1, xWb, att1, ns, 1, Nn,
                                               ent_feat, gw, aw, lw, idemb, num_ent);
    agg_node<<<agg_blocks, blk, 0, stream>>>(offs, sorted, xWb, rw16, ns, srt, x1b, 1, (int)Nn);

    // ---------------- Layer 2 ----------------
    prep2<<<2 * nrel, D, 0, stream>>>(r1, W2, Wr2, att2, rw16, r2, srt, nrel);
    gemm_mfma<<<gemm_blocks, blk, 0, stream>>>(x1b, Wt2, xWb, att2, ns, 2, Nn,
                                               nullptr, nullptr, nullptr, nullptr, nullptr, num_ent);
    agg_node<<<agg_blocks, blk, 0, stream>>>(offs, sorted, xWb, rw16, ns, srt, out_x, 0, (int)Nn);

    // ---------------- outputs ----------------
    gather_out<<<gat_blocks, blk, 0, stream>>>(sub, rel, out_x, r2, out_sub, out_rel, Bn);
}

// Round 19
// 276.668 us; speedup vs baseline: 1.4034x; 1.0001x over previous
//
#include <hip/hip_runtime.h>

#define D 128
#define HEADS 4

typedef __attribute__((ext_vector_type(8))) short short8;
typedef __attribute__((ext_vector_type(4))) short s16x4;
typedef __attribute__((ext_vector_type(4))) float f32x4;

// f32 -> bf16 (round to nearest even), bit pattern in short
__device__ __forceinline__ short f2b(float f) {
    unsigned u = __float_as_uint(f);
    unsigned r = (u + 0x7FFFu + ((u >> 16) & 1u)) >> 16;
    return (short)r;
}

__device__ __forceinline__ float fast_tanh(float x) {
    float e = __expf(2.0f * x);
    return 1.0f - 2.0f / (e + 1.0f);   // exact at +-inf; ~1e-7 rel err
}

// ---------- MFMA GEMM: C[M,128](bf16) = A[M,128] @ W[128,128] ----------
// 2 row-tiles (128 rows) per block; swapped-operand MFMA (row-major C frags);
// 8x8B C stores; register-space ns epilogue.
__global__ __launch_bounds__(256) void gemm_mfma(
    const unsigned short* __restrict__ Ab, const short* __restrict__ Wt,
    unsigned short* __restrict__ C, const float* __restrict__ att,
    float* __restrict__ ns, int buildmode, long Mrows,
    const int* __restrict__ ent_feature, const float* __restrict__ gw,
    const float* __restrict__ aw, const float* __restrict__ lw,
    const float* __restrict__ idemb, int num_ent)
{
    __shared__ short sA[64 * D];    // 16 KB, 16B granules XOR-swizzled by row&7
    __shared__ short sW[D * D];     // 32 KB
    __shared__ float attL[256];     // 1 KB att copy

    const int t = threadIdx.x;

    // ---- stage Wt once + att copy ----
    #pragma unroll
    for (int i = 0; i < 8; ++i) {
        int c = t + 256 * i;         // granule id
        int row = c >> 4, kb = c & 15;
        short8 blk = *(const short8*)(Wt + c * 8);
        *(short8*)&sW[row * D + (kb ^ (row & 7)) * 8] = blk;
    }
    attL[t] = att[t];

    for (int sub = 0; sub < 2; ++sub) {
        const long row0 = (long)blockIdx.x * 128 + sub * 64;
        if (row0 >= Mrows) break;          // uniform
        if (sub) __syncthreads();          // protect sA reuse

        // ---- stage A tile: 1 thread = 1 row-quarter (32 elems) ----
        {
            int srow = t >> 2;           // 0..63
            int q = t & 3;               // k-quarter
            long grow = row0 + srow;
            if (buildmode == 2) {
                const short8* p8 = (const short8*)(Ab + grow * D);
                #pragma unroll
                for (int jb = 0; jb < 4; ++jb) {
                    short8 blk = p8[q * 4 + jb];
                    int kb = (q * 4 + jb) ^ (srow & 7);
                    *(short8*)&sA[srow * D + kb * 8] = blk;
                }
            } else {
                const float* srcp;
                if (grow < num_ent)               srcp = idemb + grow * D;
                else if (grow < 2L * num_ent)     srcp = gw + (long)ent_feature[(grow - num_ent) * 3 + 0] * D;
                else if (grow < 3L * num_ent)     srcp = aw + (long)ent_feature[(grow - 2L * num_ent) * 3 + 1] * D;
                else                              srcp = lw + (long)ent_feature[(grow - 3L * num_ent) * 3 + 2] * D;
                const float4* p4 = (const float4*)srcp + q * 8;
                float v[32];
                #pragma unroll
                for (int j = 0; j < 8; ++j) {
                    float4 f = p4[j];
                    v[j * 4 + 0] = f.x; v[j * 4 + 1] = f.y; v[j * 4 + 2] = f.z; v[j * 4 + 3] = f.w;
                }
                #pragma unroll
                for (int jb = 0; jb < 4; ++jb) {
                    short8 blk;
                    #pragma unroll
                    for (int e = 0; e < 8; ++e) blk[e] = f2b(v[jb * 8 + e]);
                    int kb = (q * 4 + jb) ^ (srow & 7);
                    *(short8*)&sA[srow * D + kb * 8] = blk;
                }
            }
        }
        __syncthreads();

        // ---- MFMA (swapped operands): wave wv covers A-rows [wv*16, wv*16+16) ----
        const int wv = t >> 6, lane = t & 63;
        const int cl = lane & 15, kg = lane >> 4;

        short8 a[4];
        #pragma unroll
        for (int ks = 0; ks < 4; ++ks)
            a[ks] = *(const short8*)&sA[(wv * 16 + cl) * D + (((ks * 4 + kg) ^ (cl & 7)) * 8)];

        f32x4 acc[8];
        #pragma unroll
        for (int ct = 0; ct < 8; ++ct) acc[ct] = (f32x4){0.f, 0.f, 0.f, 0.f};

        #pragma unroll
        for (int ct = 0; ct < 8; ++ct) {
            #pragma unroll
            for (int ks = 0; ks < 4; ++ks) {
                short8 b = *(const short8*)&sW[(ct * 16 + cl) * D + (((ks * 4 + kg) ^ (cl & 7)) * 8)];
                acc[ct] = __builtin_amdgcn_mfma_f32_16x16x32_bf16(b, a[ks], acc[ct], 0, 0, 0);
            }
        }

        // ---- C store: lane holds C[row0+wv*16+cl][ct*16+kg*4 .. +3] per ct ----
        {
            unsigned short* Crow = C + (row0 + wv * 16 + cl) * D + kg * 4;
            #pragma unroll
            for (int ct = 0; ct < 8; ++ct) {
                s16x4 v;
                #pragma unroll
                for (int j = 0; j < 4; ++j) v[j] = f2b(acc[ct][j]);
                *(s16x4*)(Crow + ct * 16) = v;
            }
        }

        // ---- ns epilogue: per-lane partials + kg-axis reduction ----
        {
            float qp[4] = {0.f, 0.f, 0.f, 0.f};
            float sp[4] = {0.f, 0.f, 0.f, 0.f};
            #pragma unroll
            for (int ct = 0; ct < 8; ++ct) {
                int h = ct >> 1;
                int base = h * 64 + (ct & 1) * 16 + kg * 4;
                f32x4 aq4 = *(const f32x4*)&attL[base];
                f32x4 am4 = *(const f32x4*)&attL[base + 32];
                #pragma unroll
                for (int j = 0; j < 4; ++j) {
                    qp[h] = fmaf(acc[ct][j], aq4[j], qp[h]);
                    sp[h] = fmaf(acc[ct][j], am4[j], sp[h]);
                }
            }
            #pragma unroll
            for (int h = 0; h < 4; ++h) {
                qp[h] += __shfl_xor(qp[h], 16);
                qp[h] += __shfl_xor(qp[h], 32);
                sp[h] += __shfl_xor(sp[h], 16);
                sp[h] += __shfl_xor(sp[h], 32);
            }
            float qv = qp[0], sv = sp[0];
            if (kg == 1) { qv = qp[1]; sv = sp[1]; }
            else if (kg == 2) { qv = qp[2]; sv = sp[2]; }
            else if (kg == 3) { qv = qp[3]; sv = sp[3]; }
            long rown = row0 + wv * 16 + cl;
            ns[rown * 8 + kg] = qv;
            ns[rown * 8 + 4 + kg] = sv;
        }
    }
}

// ---------- prep1: fused {rw16_1 (bf16 r@W1), srt1, r1=r@Wr1, Wt1, Wt2} ----------
__global__ void prep1(const float* __restrict__ init_rel,
                      const float* __restrict__ W1, const float* __restrict__ Wr1,
                      const float* __restrict__ W2, const float* __restrict__ att1,
                      unsigned short* __restrict__ rw16, float* __restrict__ r1,
                      float* __restrict__ srt,
                      short* __restrict__ Wt1, short* __restrict__ Wt2, int nrel)
{
    __shared__ float red[128];
    int b = blockIdx.x, c = threadIdx.x;
    if (b >= 2 * nrel) {
        int bb = b - 2 * nrel;
        const float* W = (bb < D) ? W1 : W2;
        short* Wt = (bb < D) ? Wt1 : Wt2;
        int n = bb & (D - 1);
        Wt[n * D + c] = f2b(W[c * D + n]);
        return;
    }
    int r = (b < nrel) ? b : b - nrel;
    const float* W = (b < nrel) ? W1 : Wr1;
    float s = 0.f;
    for (int k = 0; k < D; ++k) s = fmaf(init_rel[r * D + k], W[k * D + c], s);
    if (b < nrel) {
        rw16[r * D + c] = (unsigned short)f2b(s);
        int h = c >> 5;
        red[c] = s * att1[h * 64 + 32 + (c & 31)];
        __syncthreads();
        if (c < 4) {
            float ss = 0.f;
            #pragma unroll
            for (int k = 0; k < 32; ++k) ss += red[c * 32 + k];
            srt[r * 4 + c] = ss;
        }
    } else {
        r1[r * D + c] = s;
    }
}

// ---------- prep2: fused {rw16_2 (bf16 r1@W2), srt2, r2=r1@Wr2} ----------
__global__ void prep2(const float* __restrict__ r1,
                      const float* __restrict__ W2, const float* __restrict__ Wr2,
                      const float* __restrict__ att2,
                      unsigned short* __restrict__ rw16, float* __restrict__ r2,
                      float* __restrict__ srt, int nrel)
{
    __shared__ float red[128];
    int b = blockIdx.x, c = threadIdx.x;
    int r = (b < nrel) ? b : b - nrel;
    const float* W = (b < nrel) ? W2 : Wr2;
    float s = 0.f;
    for (int k = 0; k < D; ++k) s = fmaf(r1[r * D + k], W[k * D + c], s);
    if (b < nrel) {
        rw16[r * D + c] = (unsigned short)f2b(s);
        int h = c >> 5;
        red[c] = s * att2[h * 64 + 32 + (c & 31)];
        __syncthreads();
        if (c < 4) {
            float ss = 0.f;
            #pragma unroll
            for (int k = 0; k < 32; ++k) ss += red[c * 32 + k];
            srt[r * 4 + c] = ss;
        }
    } else {
        r2[r * D + c] = s;
    }
}

// ---------- CSR build (split kernels) ----------
__global__ __launch_bounds__(256) void hist_deg(const int* __restrict__ dst,
                                                int* __restrict__ deg, int E_)
{
    int i = blockIdx.x * 256 + threadIdx.x;
    if (i < E_) atomicAdd(&deg[dst[i]], 1);
}

__global__ __launch_bounds__(256) void scan_local(const int* __restrict__ deg,
                                                  int* __restrict__ offs,
                                                  int* __restrict__ partial, int n)
{
    __shared__ int lds[256];
    int b = blockIdx.x, t = threadIdx.x;
    int base = b * 1024;
    int v[4]; int s = 0;
    #pragma unroll
    for (int j = 0; j < 4; ++j) {
        int idx = base + t * 4 + j;
        v[j] = idx < n ? deg[idx] : 0;
        s += v[j];
    }
    lds[t] = s;
    __syncthreads();
    int mysum = s;
    for (int off = 1; off < 256; off <<= 1) {
        int o = t >= off ? lds[t - off] : 0;
        __syncthreads();
        lds[t] += o;
        __syncthreads();
    }
    int excl = lds[t] - mysum;
    if (t == 255) partial[b] = lds[255];
    int run = excl;
    #pragma unroll
    for (int j = 0; j < 4; ++j) {
        int idx = base + t * 4 + j;
        if (idx < n) offs[idx] = run;
        run += v[j];
    }
}

// parallel scan of block partials (nb <= 256), one 256-thread block
__global__ void scan_partials(int* __restrict__ partial, int nb,
                              int* __restrict__ offs, int n)
{
    __shared__ int lds[256];
    int t = threadIdx.x;
    int v = (t < nb) ? partial[t] : 0;
    lds[t] = v;
    __syncthreads();
    int my = v;
    for (int off = 1; off < 256; off <<= 1) {
        int o = (t >= off) ? lds[t - off] : 0;
        __syncthreads();
        lds[t] += o;
        __syncthreads();
    }
    if (t < nb) partial[t] = lds[t] - my;    // exclusive
    if (t == 255) offs[n] = lds[255];
}

__global__ __launch_bounds__(256) void scan_add(int* __restrict__ offs,
                                                const int* __restrict__ partial, int n)
{
    int idx = blockIdx.x * 256 + threadIdx.x;
    if (idx < n) offs[idx] += partial[idx >> 10];
}

// scatter: cursor = deg counting down (atomicSub); pack (src<<8)|etype
__global__ __launch_bounds__(256) void scatter_edges(
    const int* __restrict__ src, const int* __restrict__ dst, const int* __restrict__ etype,
    const int* __restrict__ offs, int* __restrict__ deg,
    unsigned* __restrict__ sorted, int E_)
{
    int i = blockIdx.x * 256 + threadIdx.x;
    if (i >= E_) return;
    int d = dst[i];
    int pos = offs[d] + atomicSub(&deg[d], 1) - 1;
    sorted[pos] = ((unsigned)src[i] << 8) | (unsigned)etype[i];
}

// ---------- fused per-node aggregation: inline score, grid-stride, offs-prefetch ----------
// 256-thread blocks = 4 waves; lane l covers elems [2l, 2l+1]; head = l>>4
#define GATHER_SLOT(mb, sv, rv, sr, p, cond)                                 \
    unsigned mb = 0, rv = 0; float sv = 0.f, sr = 0.f;                       \
    if (cond) { unsigned rowb = (p) & 0xFFFFFF00u;                           \
        unsigned etb = ((p) & 0xFFu) << 8;                                   \
        mb = *(const unsigned*)(xb + rowb + lo4);                            \
        sv = *(const float*)(nb + (rowb >> 3) + ho4);                        \
        rv = *(const unsigned*)(rb + etb + lo4);                             \
        sr = *(const float*)(sb + (etb >> 4) + (ho4 - 16)); }

#define ACCUM_SLOT(mb, sv, rv, sr, cond)                                     \
    if (cond) {                                                              \
        float mx = __uint_as_float(mb << 16) + __uint_as_float(rv << 16);    \
        float my = __uint_as_float(mb & 0xFFFF0000u) + __uint_as_float(rv & 0xFFFF0000u); \
        float sc = qd + sv + sr; sc = sc > 0.f ? sc : 0.2f * sc;             \
        float we = __expf(sc);                                               \
        srun += we; ax = fmaf(we, mx, ax); ay = fmaf(we, my, ay); }

__global__ __launch_bounds__(256) void agg_node(
    const int* __restrict__ offs, const unsigned* __restrict__ sedge,
    const unsigned short* __restrict__ xWb, const unsigned short* __restrict__ rw16,
    const float* __restrict__ ns, const float* __restrict__ srt,
    void* __restrict__ outx, int out_bf16, int Nn)
{
    int wid = threadIdx.x >> 6;
    int lane = threadIdx.x & 63;
    int h = lane >> 4;

    const char* xb = (const char*)xWb;
    const char* rb = (const char*)rw16;
    const char* nb = (const char*)ns;
    const char* sb = (const char*)srt;
    const int lo4 = 4 * lane;
    const int ho4 = 16 + 4 * h;      // sm part of ns row (+16 B); srt uses ho4-16

    const long wstride = (long)gridDim.x * 4;
    long node = (long)blockIdx.x * 4 + wid;
    if (node >= Nn) return;

    // pipeline head: current node's extent
    int e0 = offs[node], e1 = offs[node + 1];

    while (true) {
        // ---- prefetch next node's extent (overlaps current node's chain) ----
        long nnext = node + wstride;
        int e0n = 0, e1n = 0;
        if (nnext < Nn) {
            e0n = offs[nnext];
            e1n = offs[nnext + 1];
        }

        float qd = ns[node * 8 + h];
        float srun = 0.f, ax = 0.f, ay = 0.f;

        for (int base = e0; base < e1; base += 4) {
            unsigned p0 = sedge[base];
            unsigned p1 = (base + 1 < e1) ? sedge[base + 1] : 0;
            unsigned p2 = (base + 2 < e1) ? sedge[base + 2] : 0;
            unsigned p3 = (base + 3 < e1) ? sedge[base + 3] : 0;

            GATHER_SLOT(m0, v0, r0, s0, p0, true)
            GATHER_SLOT(m1, v1, r1, s1, p1, base + 1 < e1)
            GATHER_SLOT(m2, v2, r2, s2, p2, base + 2 < e1)
            GATHER_SLOT(m3, v3, r3, s3, p3, base + 3 < e1)

            ACCUM_SLOT(m0, v0, r0, s0, true)
            ACCUM_SLOT(m1, v1, r1, s1, base + 1 < e1)
            ACCUM_SLOT(m2, v2, r2, s2, base + 2 < e1)
            ACCUM_SLOT(m3, v3, r3, s3, base + 3 < e1)
        }

        float inv = 1.0f / (srun + 1e-16f);
        float ox = fast_tanh(ax * inv);
        float oy = fast_tanh(ay * inv);
        if (out_bf16) {
            unsigned pk = ((unsigned)(unsigned short)f2b(oy) << 16) | (unsigned short)f2b(ox);
            *(unsigned*)((unsigned short*)outx + node * D + 2 * lane) = pk;
        } else {
            float2 o; o.x = ox; o.y = oy;
            *(float2*)((float*)outx + node * D + 2 * lane) = o;
        }

        if (nnext >= Nn) break;
        node = nnext; e0 = e0n; e1 = e1n;
    }
}

// ---------- combined output gathers: sub from out_x, rel from r2 ----------
__global__ void gather_out(const int* __restrict__ sub, const int* __restrict__ rel,
                           const float* __restrict__ xsrc, const float* __restrict__ rsrc,
                           float* __restrict__ out_sub, float* __restrict__ out_rel, int b)
{
    long i = (long)blockIdx.x * 256 + threadIdx.x;
    long tot = (long)b * 32;
    if (i < tot) {
        long row = i >> 5; int q = (int)(i & 31);
        ((float4*)out_sub)[i] = ((const float4*)(xsrc + (long)sub[row] * D))[q];
    } else if (i < 2 * tot) {
        long j = i - tot;
        long row = j >> 5; int q = (int)(j & 31);
        ((float4*)out_rel)[j] = ((const float4*)(rsrc + (long)rel[row] * D))[q];
    }
}

extern "C" void kernel_launch(void* const* d_in, const int* in_sizes, int n_in,
                              void* d_out, int out_size, void* d_ws, size_t ws_size,
                              hipStream_t stream)
{
    const int*   sub        = (const int*)d_in[0];
    const int*   rel        = (const int*)d_in[1];
    const int*   edge_index = (const int*)d_in[2];
    const int*   edge_type  = (const int*)d_in[3];
    const int*   ent_feat   = (const int*)d_in[4];
    const float* gw         = (const float*)d_in[5];
    const float* aw         = (const float*)d_in[6];
    const float* lw         = (const float*)d_in[7];
    const float* idemb      = (const float*)d_in[8];
    const float* init_rel   = (const float*)d_in[9];
    const float* W1         = (const float*)d_in[10];
    const float* Wr1        = (const float*)d_in[11];
    const float* att1       = (const float*)d_in[12];
    const float* W2         = (const float*)d_in[13];
    const float* Wr2        = (const float*)d_in[14];
    const float* att2       = (const float*)d_in[15];

    const int  Bn      = in_sizes[0];
    const int  E_      = in_sizes[3];
    const int  num_ent = in_sizes[4] / 3;
    const long Nn      = 4L * num_ent;
    const int  nrel    = in_sizes[9] / D;

    const int* srcp = edge_index;
    const int* dstp = edge_index + E_;

    float* out_sub = (float*)d_out;
    float* out_rel = out_sub + (long)Bn * D;
    float* out_x   = out_rel + (long)Bn * D;   // N x 128 final x (f32)

    unsigned short* xWb = (unsigned short*)d_ws;       // N x 128 bf16
    unsigned short* x1b = xWb + Nn * D;                // N x 128 bf16
    int*      offs   = (int*)(x1b + Nn * D);           // N+4 (padded)
    int*      deg    = offs + (Nn + 4);                // N (also scatter cursor)
    unsigned* sorted = (unsigned*)(deg + Nn);          // E packed (src<<8)|et
    int*      partial= (int*)(sorted + E_);            // block partials (1024)
    unsigned short* rw16 = (unsigned short*)(partial + 1024);  // nrel x 128 bf16
    float* r1     = (float*)(rw16 + (long)nrel * D);
    float* r2     = r1 + (long)nrel * D;
    short* Wt1    = (short*)(r2 + (long)nrel * D);     // 128x128 bf16
    short* Wt2    = Wt1 + D * D;
    float* ns     = (float*)(Wt2 + D * D);             // N x 8
    float* srt    = ns + Nn * 8;                       // nrel x 4

    dim3 blk(256);
    int gemm_blocks  = (int)((Nn + 127) / 128);
    int e_blocks     = (E_ + 255) / 256;
    int agg_blocks   = 2048;                           // grid-stride
    int gat_blocks   = (int)((2L * Bn * 32 + 255) / 256);
    int scan_blocks  = (int)((Nn + 1023) / 1024);
    int sadd_blocks  = (int)((Nn + 255) / 256);

    // ---------------- prep1: Wt transposes + rel GEMMs + srt1 ----------------
    prep1<<<2 * nrel + 256, D, 0, stream>>>(init_rel, W1, Wr1, W2, att1,
                                            rw16, r1, srt, Wt1, Wt2, nrel);

    // ---------------- CSR build (by dst), split kernels ----------------
    hipMemsetAsync(deg, 0, Nn * sizeof(int), stream);
    hist_deg<<<e_blocks, blk, 0, stream>>>(dstp, deg, E_);
    scan_local<<<scan_blocks, blk, 0, stream>>>(deg, offs, partial, (int)Nn);
    scan_partials<<<1, 256, 0, stream>>>(partial, scan_blocks, offs, (int)Nn);
    scan_add<<<sadd_blocks, blk, 0, stream>>>(offs, partial, (int)Nn);
    scatter_edges<<<e_blocks, blk, 0, stream>>>(srcp, dstp, edge_type, offs, deg, sorted, E_);

    // ---------------- Layer 1 ----------------
    gemm_mfma<<<gemm_blocks, blk, 0, stream>>>(nullptr, Wt1, xWb, att1, ns, 1, Nn,
                                               ent_feat, gw, aw, lw, idemb, num_ent);
    agg_node<<<agg_blocks, blk, 0, stream>>>(offs, sorted, xWb, rw16, ns, srt, x1b, 1, (int)Nn);

    // ---------------- Layer 2 ----------------
    prep2<<<2 * nrel, D, 0, stream>>>(r1, W2, Wr2, att2, rw16, r2, srt, nrel);
    gemm_mfma<<<gemm_blocks, blk, 0, stream>>>(x1b, Wt2, xWb, att2, ns, 2, Nn,
                                               nullptr, nullptr, nullptr, nullptr, nullptr, num_ent);
    agg_node<<<agg_blocks, blk, 0, stream>>>(offs, sorted, xWb, rw16, ns, srt, out_x, 0, (int)Nn);

    // ---------------- outputs ----------------
    gather_out<<<gat_blocks, blk, 0, stream>>>(sub, rel, out_x, r2, out_sub, out_rel, Bn);
}